// Round 1
// baseline (288.645 us; speedup 1.0000x reference)
//
#include <hip/hip_runtime.h>

typedef __bf16 bf16x8 __attribute__((ext_vector_type(8)));
typedef float f32x4 __attribute__((ext_vector_type(4)));

__device__ __forceinline__ unsigned short f2bf(float f) {
    union { float f; unsigned int u; } v; v.f = f;
    unsigned int u = v.u;
    unsigned int r = (u + 0x7fffu + ((u >> 16) & 1u)) >> 16;
    return (unsigned short)r;
}

// ---------------------------------------------------------------------------
// Kernel 1: reconstruct TT conv weights -> bf16 in MFMA-friendly layout.
// W[d][c][kh][kw] = sum_{r,s} core0[d,c,r] * core1[d,r,kh,s] * core2[d,s,kw]
// K-index: kidx = (kh*3+kw)*128 + c   (tap-major, c fastest within tap)
// Stored at wb[(kidx>>3)*2048 + d*8 + (kidx&7)]  == [kchunk][ko8][d][j]
// so a 32-k chunk is a contiguous 16 KB block and each lane's A-fragment
// (8 consecutive k for one d) is one 16B ds_read_b128.
// ---------------------------------------------------------------------------
__global__ void build_w_kernel(const float* __restrict__ core0,
                               const float* __restrict__ core1,
                               const float* __restrict__ core2,
                               unsigned short* __restrict__ wb) {
    __shared__ float s1[96];   // core1[d]: [r][kh][s] = 8*3*4
    __shared__ float s2[12];   // core2[d]: [s][kw]   = 4*3
    const int d = blockIdx.x;
    const int c = threadIdx.x;   // 128 threads
    if (c < 96) s1[c] = core1[d * 96 + c];
    if (c >= 96 && c < 108) s2[c - 96] = core2[d * 12 + (c - 96)];
    __syncthreads();
    float t0[8];
#pragma unroll
    for (int r = 0; r < 8; ++r) t0[r] = core0[(d * 128 + c) * 8 + r];
#pragma unroll
    for (int kh = 0; kh < 3; ++kh) {
        float v[4] = {0.f, 0.f, 0.f, 0.f};
#pragma unroll
        for (int r = 0; r < 8; ++r)
#pragma unroll
            for (int s = 0; s < 4; ++s)
                v[s] += t0[r] * s1[(r * 3 + kh) * 4 + s];
#pragma unroll
        for (int kw = 0; kw < 3; ++kw) {
            float val = 0.f;
#pragma unroll
            for (int s = 0; s < 4; ++s) val += v[s] * s2[s * 3 + kw];
            const int kidx = (kh * 3 + kw) * 128 + c;
            wb[(kidx >> 3) * 2048 + d * 8 + (kidx & 7)] = f2bf(val);
        }
    }
}

// ---------------------------------------------------------------------------
// Kernel 2: implicit-GEMM conv. One block per (n, h): computes
// out[n, 0:256, h, 0:64]. M-tile = 64 pixels (one row), N-tile = 256 d.
// LDS: x rows h-1..h+1 as bf16 [row][wcol 0..65][c padded to 136],
//      weight chunk [ko8][d][j] (16 KB), single-buffered (m97 structure).
// Per wave per chunk: 4 A-frag + 4 B-frag ds_read_b128, 16 MFMA 16x16x32.
// A = weights (m = d), B = pixels (n = w)  =>  D: row=d, col=w -> coalesced.
// ---------------------------------------------------------------------------
#define LC 136   // padded c dimension (128 + 8): 2-way-only LDS bank aliasing

__global__ __launch_bounds__(256) void conv_mfma_kernel(
    const float* __restrict__ x, const unsigned short* __restrict__ wb,
    const float* __restrict__ bias, float* __restrict__ out) {
    __shared__ __align__(16) unsigned short xl[3 * 66 * LC];   // 53,856 B
    __shared__ __align__(16) unsigned short bl[32 * 256];      // 16,384 B

    const int tid  = threadIdx.x;
    const int lane = tid & 63;
    const int wv   = tid >> 6;
    const int l15  = lane & 15;
    const int quad = lane >> 4;
    const int bid  = blockIdx.x;
    const int n    = bid >> 6;
    const int h    = bid & 63;

    // ---- zero the x tile (covers halo + padding) ----
    uint4* xz = (uint4*)xl;
    const uint4 z4 = make_uint4(0u, 0u, 0u, 0u);
    for (int i = tid; i < (3 * 66 * LC * 2) / 16; i += 256) xz[i] = z4;
    __syncthreads();

    // ---- stage x rows h-1..h+1 as bf16, layout [row][wcol][c] ----
    // index space: row(3) x cgroup(32) x w4(16); each thread-iter moves
    // 4 c-planes x 4 w  (4x float4 coalesced loads -> 4x ds_write_b64)
#pragma unroll
    for (int i = 0; i < 6; ++i) {
        const int it  = tid + (i << 8);
        const int w4  = it & 15;
        const int cg  = (it >> 4) & 31;
        const int row = it >> 9;
        const int rimg = h + row - 1;
        if (rimg >= 0 && rimg < 64) {
            const int c = cg << 2;
            const int w = w4 << 2;
            const float4* gp = (const float4*)(x + (((n * 128 + c) * 64 + rimg) * 64 + w));
            const float4 p0 = gp[0];
            const float4 p1 = gp[1024];   // +1 c-plane (64*64 floats)
            const float4 p2 = gp[2048];
            const float4 p3 = gp[3072];
            unsigned short* base = xl + (row * 66 + w + 1) * LC + c;
            *(ushort4*)(base)           = make_ushort4(f2bf(p0.x), f2bf(p1.x), f2bf(p2.x), f2bf(p3.x));
            *(ushort4*)(base + LC)      = make_ushort4(f2bf(p0.y), f2bf(p1.y), f2bf(p2.y), f2bf(p3.y));
            *(ushort4*)(base + 2 * LC)  = make_ushort4(f2bf(p0.z), f2bf(p1.z), f2bf(p2.z), f2bf(p3.z));
            *(ushort4*)(base + 3 * LC)  = make_ushort4(f2bf(p0.w), f2bf(p1.w), f2bf(p2.w), f2bf(p3.w));
        }
    }
    // staging is made visible by the barrier at the top of chunk 0

    f32x4 acc[4][4];
#pragma unroll
    for (int a0 = 0; a0 < 4; ++a0)
#pragma unroll
        for (int b0 = 0; b0 < 4; ++b0) acc[a0][b0] = (f32x4){0.f, 0.f, 0.f, 0.f};

    const uint4* wg = (const uint4*)wb;   // 1024 uint4 per 16 KB chunk
    uint4 rw0 = wg[tid], rw1 = wg[tid + 256], rw2 = wg[tid + 512], rw3 = wg[tid + 768];

    const int dwave = wv << 6;     // 64 d-channels per wave
    uint4* blv = (uint4*)bl;

    for (int ch = 0; ch < 36; ++ch) {
        __syncthreads();           // previous chunk's reads (or x staging) done
        blv[tid]       = rw0;
        blv[tid + 256] = rw1;
        blv[tid + 512] = rw2;
        blv[tid + 768] = rw3;
        __syncthreads();
        if (ch + 1 < 36) {         // prefetch next chunk, overlap with MFMA
            const uint4* g2 = wg + (ch + 1) * 1024;
            rw0 = g2[tid]; rw1 = g2[tid + 256]; rw2 = g2[tid + 512]; rw3 = g2[tid + 768];
        }
        const int tap = ch >> 2;         // 0..8  = 3*kh + kw
        const int kh  = tap / 3;
        const int kw  = tap - kh * 3;
        const int c0  = (ch & 3) << 5;   // c base within tap

        bf16x8 af[4], bfr[4];
        const unsigned short* ap = bl + (quad * 256 + dwave + l15) * 8;
#pragma unroll
        for (int dt = 0; dt < 4; ++dt) af[dt] = *(const bf16x8*)(ap + dt * 128);
        const unsigned short* bp = xl + (kh * 66 + l15 + kw) * LC + c0 + quad * 8;
#pragma unroll
        for (int pt = 0; pt < 4; ++pt) bfr[pt] = *(const bf16x8*)(bp + pt * 16 * LC);

#pragma unroll
        for (int dt = 0; dt < 4; ++dt)
#pragma unroll
            for (int pt = 0; pt < 4; ++pt)
                acc[dt][pt] = __builtin_amdgcn_mfma_f32_16x16x32_bf16(
                    af[dt], bfr[pt], acc[dt][pt], 0, 0, 0);
    }

    // ---- epilogue: bias + store. D layout: row(d) = quad*4+r, col(w) = l15 ----
    const float bv = bias[0];
#pragma unroll
    for (int dt = 0; dt < 4; ++dt) {
#pragma unroll
        for (int pt = 0; pt < 4; ++pt) {
#pragma unroll
            for (int r = 0; r < 4; ++r) {
                const int d = dwave + dt * 16 + quad * 4 + r;
                const int w = pt * 16 + l15;
                out[((n * 256 + d) * 64 + h) * 64 + w] = acc[dt][pt][r] + bv;
            }
        }
    }
}

extern "C" void kernel_launch(void* const* d_in, const int* in_sizes, int n_in,
                              void* d_out, int out_size, void* d_ws, size_t ws_size,
                              hipStream_t stream) {
    const float* x     = (const float*)d_in[0];
    const float* core0 = (const float*)d_in[1];
    const float* core1 = (const float*)d_in[2];
    const float* core2 = (const float*)d_in[3];
    const float* bias  = (const float*)d_in[4];
    unsigned short* wb = (unsigned short*)d_ws;   // 1152*256*2 = 589,824 B

    build_w_kernel<<<256, 128, 0, stream>>>(core0, core1, core2, wb);
    conv_mfma_kernel<<<2048, 256, 0, stream>>>(x, wb, bias, (float*)d_out);
}

// Round 2
// 248.758 us; speedup vs baseline: 1.1603x; 1.1603x over previous
//
#include <hip/hip_runtime.h>

typedef __bf16 bf16x8 __attribute__((ext_vector_type(8)));
typedef float f32x4 __attribute__((ext_vector_type(4)));

__device__ __forceinline__ unsigned short f2bf(float f) {
    union { float f; unsigned int u; } v; v.f = f;
    unsigned int u = v.u;
    unsigned int r = (u + 0x7fffu + ((u >> 16) & 1u)) >> 16;
    return (unsigned short)r;
}

// ---------------------------------------------------------------------------
// Kernel 1: reconstruct TT conv weights -> bf16, MFMA-A-fragment layout.
// kidx = (kh*3+kw)*128 + c ; stored wb[(kidx>>3)*2048 + d*8 + (kidx&7)]
// => one lane's A-frag (8 consecutive k, one d) is one contiguous 16 B load,
//    lanes (consecutive d) are consecutive 16 B => fully coalesced global load.
// ---------------------------------------------------------------------------
__global__ void build_w_kernel(const float* __restrict__ core0,
                               const float* __restrict__ core1,
                               const float* __restrict__ core2,
                               unsigned short* __restrict__ wb) {
    __shared__ float s1[96];   // core1[d]: [r][kh][s]
    __shared__ float s2[12];   // core2[d]: [s][kw]
    const int d = blockIdx.x;
    const int c = threadIdx.x;   // 128 threads
    if (c < 96) s1[c] = core1[d * 96 + c];
    if (c >= 96 && c < 108) s2[c - 96] = core2[d * 12 + (c - 96)];
    __syncthreads();
    float t0[8];
#pragma unroll
    for (int r = 0; r < 8; ++r) t0[r] = core0[(d * 128 + c) * 8 + r];
#pragma unroll
    for (int kh = 0; kh < 3; ++kh) {
        float v[4] = {0.f, 0.f, 0.f, 0.f};
#pragma unroll
        for (int r = 0; r < 8; ++r)
#pragma unroll
            for (int s = 0; s < 4; ++s)
                v[s] += t0[r] * s1[(r * 3 + kh) * 4 + s];
#pragma unroll
        for (int kw = 0; kw < 3; ++kw) {
            float val = 0.f;
#pragma unroll
            for (int s = 0; s < 4; ++s) val += v[s] * s2[s * 3 + kw];
            const int kidx = (kh * 3 + kw) * 128 + c;
            wb[(kidx >> 3) * 2048 + d * 8 + (kidx & 7)] = f2bf(val);
        }
    }
}

// ---------------------------------------------------------------------------
// Kernel 2: implicit-GEMM conv, barrier-free K-loop.
// One block per (n, h): out[n, 0:256, h, 0:64]. M=64 pixels, N=256 d, K=1152.
// x rows h-1..h+1 staged once in LDS as bf16 [row][wcol 0..65][c pad 136];
// ONE __syncthreads(); then 36 chunks of: 4 A-frags DIRECT FROM GLOBAL
// (L2-resident, coalesced, prefetched 1 chunk ahead) + 4 B-frag ds_read_b128
// + 16 MFMA 16x16x32 — no barriers, no weight LDS round-trip.
// LDS = 53,856 B < 160KiB/3  =>  3 blocks/CU (vs 2 before).
// ---------------------------------------------------------------------------
#define LC 136   // padded c dim: byte stride 272 => 16B-granule stride 17 ≡ 1 (mod 8)
                 // => each group of 8 lanes covers all 8 bank-quads: conflict-free b128

__global__ __launch_bounds__(256, 3) void conv_mfma_kernel(
    const float* __restrict__ x, const unsigned short* __restrict__ wb,
    const float* __restrict__ bias, float* __restrict__ out) {
    __shared__ __align__(16) unsigned short xl[3 * 66 * LC];   // 53,856 B

    const int tid  = threadIdx.x;
    const int lane = tid & 63;
    const int wv   = tid >> 6;
    const int l15  = lane & 15;
    const int quad = lane >> 4;
    const int bid  = blockIdx.x;
    const int n    = bid >> 6;
    const int h    = bid & 63;

    // ---- zero halo columns (wcol 0 and 65) only: 3 rows x 2 cols x 128 c ----
    if (tid < 96) {
        const int row = tid >> 5;
        const int j   = tid & 31;
        const int col = (j >> 4) ? 65 : 0;
        const int c   = (j & 15) << 3;
        *(uint4*)(xl + (row * 66 + col) * LC + c) = make_uint4(0u, 0u, 0u, 0u);
    }

    // ---- stage x rows h-1..h+1 as bf16 [row][wcol][c]; OOB rows write zeros ----
#pragma unroll 2
    for (int i = 0; i < 6; ++i) {
        const int it  = tid + (i << 8);
        const int w4  = it & 15;
        const int cg  = (it >> 4) & 31;
        const int row = it >> 9;
        const int rimg = h + row - 1;
        float4 p0 = make_float4(0.f, 0.f, 0.f, 0.f), p1 = p0, p2 = p0, p3 = p0;
        const int c = cg << 2;
        const int w = w4 << 2;
        if (rimg >= 0 && rimg < 64) {
            const float4* gp = (const float4*)(x + (((n * 128 + c) * 64 + rimg) * 64 + w));
            p0 = gp[0];
            p1 = gp[1024];   // +1 c-plane (64*64 floats)
            p2 = gp[2048];
            p3 = gp[3072];
        }
        unsigned short* base = xl + (row * 66 + w + 1) * LC + c;
        *(ushort4*)(base)          = make_ushort4(f2bf(p0.x), f2bf(p1.x), f2bf(p2.x), f2bf(p3.x));
        *(ushort4*)(base + LC)     = make_ushort4(f2bf(p0.y), f2bf(p1.y), f2bf(p2.y), f2bf(p3.y));
        *(ushort4*)(base + 2 * LC) = make_ushort4(f2bf(p0.z), f2bf(p1.z), f2bf(p2.z), f2bf(p3.z));
        *(ushort4*)(base + 3 * LC) = make_ushort4(f2bf(p0.w), f2bf(p1.w), f2bf(p2.w), f2bf(p3.w));
    }
    __syncthreads();   // the ONLY barrier

    f32x4 acc[4][4];
#pragma unroll
    for (int a0 = 0; a0 < 4; ++a0)
#pragma unroll
        for (int b0 = 0; b0 < 4; ++b0) acc[a0][b0] = (f32x4){0.f, 0.f, 0.f, 0.f};

    const int dwave = wv << 6;                       // 64 d per wave
    const bf16x8* wgv = (const bf16x8*)wb;           // 16 B granules
    const int abase = quad * 256 + dwave + l15;      // lane's frag index within a chunk

    // prefetch A-frags for chunk 0
    bf16x8 an[4];
#pragma unroll
    for (int dt = 0; dt < 4; ++dt) an[dt] = wgv[abase + dt * 16];

    const unsigned short* bb = xl + l15 * LC + quad * 8;

#pragma unroll
    for (int tap = 0; tap < 9; ++tap) {
        const int kh = tap / 3;
        const int kw = tap - kh * 3;
#pragma unroll
        for (int c4 = 0; c4 < 4; ++c4) {
            const int ch = tap * 4 + c4;
            bf16x8 ac[4];
#pragma unroll
            for (int dt = 0; dt < 4; ++dt) ac[dt] = an[dt];
            if (ch + 1 < 36) {
                const bf16x8* g2 = wgv + (ch + 1) * 1024 + abase;
#pragma unroll
                for (int dt = 0; dt < 4; ++dt) an[dt] = g2[dt * 16];
            }
            const int c0 = c4 << 5;
            bf16x8 bfr[4];
            const unsigned short* bp = bb + (kh * 66 + kw) * LC + c0;
#pragma unroll
            for (int pt = 0; pt < 4; ++pt) bfr[pt] = *(const bf16x8*)(bp + pt * 16 * LC);
#pragma unroll
            for (int dt = 0; dt < 4; ++dt)
#pragma unroll
                for (int pt = 0; pt < 4; ++pt)
                    acc[dt][pt] = __builtin_amdgcn_mfma_f32_16x16x32_bf16(
                        ac[dt], bfr[pt], acc[dt][pt], 0, 0, 0);
        }
    }

    // ---- epilogue: bias + store. D layout: row(d)=quad*4+r, col(w)=l15 ----
    const float bv = bias[0];
#pragma unroll
    for (int dt = 0; dt < 4; ++dt) {
#pragma unroll
        for (int pt = 0; pt < 4; ++pt) {
#pragma unroll
            for (int r = 0; r < 4; ++r) {
                const int d = dwave + dt * 16 + quad * 4 + r;
                const int w = pt * 16 + l15;
                out[((n * 256 + d) * 64 + h) * 64 + w] = acc[dt][pt][r] + bv;
            }
        }
    }
}

extern "C" void kernel_launch(void* const* d_in, const int* in_sizes, int n_in,
                              void* d_out, int out_size, void* d_ws, size_t ws_size,
                              hipStream_t stream) {
    const float* x     = (const float*)d_in[0];
    const float* core0 = (const float*)d_in[1];
    const float* core1 = (const float*)d_in[2];
    const float* core2 = (const float*)d_in[3];
    const float* bias  = (const float*)d_in[4];
    unsigned short* wb = (unsigned short*)d_ws;   // 1152*256*2 = 589,824 B

    build_w_kernel<<<256, 128, 0, stream>>>(core0, core1, core2, wb);
    conv_mfma_kernel<<<2048, 256, 0, stream>>>(x, wb, bias, (float*)d_out);
}